// Round 1
// baseline (6100.239 us; speedup 1.0000x reference)
//
#include <hip/hip_runtime.h>

#define NXD 512
#define NYD 512
#define TD 5
#define BD 4
#define HIDD 64
#define PLANE (NXD*NYD)      /* 262144 */
#define VOL (TD*PLANE)       /* 1310720 */
#define TS 16

// ---------------------------------------------------------------------------
// Fused phi_r: conv1(5->64,3x3,SAME) + bias + relu + conv2(64->5,3x3,SAME) +
// bias, then optional blend x_new = mask ? yobs : o.
// Block = 256 threads, one 16x16 output tile (all 5 channels) per block.
// x tile (20x20x5) staged in LDS; h computed in 4 chunks of 16 channels into
// LDS (18x18x16); conv2 accumulates in registers. Weights read via
// wave-uniform global loads (scalarize to s_load).
// ---------------------------------------------------------------------------
__global__ __launch_bounds__(256, 2)
void phi_kernel(const float* __restrict__ xin,
                const float* __restrict__ W1, const float* __restrict__ b1,
                const float* __restrict__ W2, const float* __restrict__ b2,
                const float* __restrict__ yobs, const int* __restrict__ mask,
                float* __restrict__ xout, int blend)
{
    __shared__ float sx[TD][20][20];     // 2000 floats
    __shared__ float sh[16][18][18];     // 5184 floats

    const int tid = threadIdx.x;
    const int b   = blockIdx.z;
    const int gx0 = blockIdx.x * TS;     // NX (H) tile origin
    const int gy0 = blockIdx.y * TS;     // NY (W) tile origin
    const float* xb = xin + (size_t)b * VOL;

    // ---- stage x tile (with halo 2), zero-padded ----
    for (int idx = tid; idx < TD * 400; idx += 256) {
        int c   = idx / 400;
        int rem = idx - c * 400;
        int u   = rem / 20;
        int v   = rem - u * 20;
        int gx  = gx0 + u - 2;
        int gy  = gy0 + v - 2;
        float val = 0.f;
        if (gx >= 0 && gx < NXD && gy >= 0 && gy < NYD)
            val = xb[c * PLANE + gx * NYD + gy];
        sx[c][u][v] = val;
    }

    float acc[TD] = {0.f, 0.f, 0.f, 0.f, 0.f};
    const int ti = tid >> 4;
    const int tj = tid & 15;

    for (int chunk = 0; chunk < 4; ++chunk) {
        const int c0 = chunk * 16;
        __syncthreads();  // sx ready (chunk 0) / sh reads of prev chunk done

        // ---- conv1: h over 18x18 region for 16 channels ----
        for (int pos = tid; pos < 324; pos += 256) {
            int i = pos / 18;
            int j = pos - i * 18;
            float xr[45];
            #pragma unroll
            for (int ci = 0; ci < 5; ++ci) {
                #pragma unroll
                for (int d = 0; d < 9; ++d)
                    xr[ci * 9 + d] = sx[ci][i + d / 3][j + d % 3];
            }
            #pragma unroll 4
            for (int c = 0; c < 16; ++c) {
                const float* w = W1 + (size_t)(c0 + c) * 45;  // uniform addr
                float h = b1[c0 + c];
                #pragma unroll
                for (int k = 0; k < 45; ++k) h = fmaf(xr[k], w[k], h);
                sh[c][i][j] = fmaxf(h, 0.f);
            }
        }
        __syncthreads();

        // ---- conv2 partial: accumulate 16 channels into 5 outputs ----
        #pragma unroll 4
        for (int c = 0; c < 16; ++c) {
            float v[9];
            #pragma unroll
            for (int d = 0; d < 9; ++d)
                v[d] = sh[c][ti + d / 3][tj + d % 3];
            #pragma unroll
            for (int co = 0; co < TD; ++co) {
                const float* w = W2 + (size_t)(co * HIDD + c0 + c) * 9;  // uniform
                float a = acc[co];
                #pragma unroll
                for (int d = 0; d < 9; ++d) a = fmaf(v[d], w[d], a);
                acc[co] = a;
            }
        }
    }

    // ---- epilogue: bias + blend + store ----
    const int gx = gx0 + ti;
    const int gy = gy0 + tj;
    const size_t base = (size_t)b * VOL + (size_t)gx * NYD + gy;
    #pragma unroll
    for (int co = 0; co < TD; ++co) {
        float o = acc[co] + b2[co];
        size_t off = base + (size_t)co * PLANE;
        if (blend) {
            int m = mask[off];
            if (m) o = yobs[off];
        }
        xout[off] = o;
    }
}

// ---------------------------------------------------------------------------
// Cost reductions for one state x: per batch
//   mse_sum = sum (gt-x)^2
//   dy_sum  = sum mask*(x-yobs)^2
//   q_sum   = sum 6.01 v^2 - 2 v (t+ neighbor + x+ neighbor + y+ neighbor)
// Accumulated via fp32 atomics into accum[b*3 + {0,1,2}].
// ---------------------------------------------------------------------------
__global__ __launch_bounds__(256)
void cost_kernel(const float* __restrict__ x, const float* __restrict__ gt,
                 const float* __restrict__ yobs, const int* __restrict__ mask,
                 float* __restrict__ accum)
{
    const int b   = blockIdx.y;
    const int idx = blockIdx.x * 256 + threadIdx.x;  // grid covers VOL exactly
    const size_t gi = (size_t)b * VOL + idx;

    const int t   = idx / PLANE;
    const int rem = idx - t * PLANE;
    const int i   = rem / NYD;
    const int j   = rem - i * NYD;

    const float v  = x[gi];
    const float g  = gt[gi];
    const float yo = yobs[gi];
    const int   m  = mask[gi];

    float mse = (g - v) * (g - v);
    float d   = v - yo;
    float dy  = m ? d * d : 0.f;
    float q   = 6.01f * v * v;
    if (t < TD - 1)  q -= 2.f * v * x[gi + PLANE];
    if (i < NXD - 1) q -= 2.f * v * x[gi + NYD];
    if (j < NYD - 1) q -= 2.f * v * x[gi + 1];

    // wave(64) reduction
    #pragma unroll
    for (int off = 32; off > 0; off >>= 1) {
        mse += __shfl_down(mse, off, 64);
        dy  += __shfl_down(dy,  off, 64);
        q   += __shfl_down(q,   off, 64);
    }
    __shared__ float red[3][4];
    const int wave = threadIdx.x >> 6;
    const int lane = threadIdx.x & 63;
    if (lane == 0) { red[0][wave] = mse; red[1][wave] = dy; red[2][wave] = q; }
    __syncthreads();
    if (threadIdx.x == 0) {
        atomicAdd(&accum[b * 3 + 0], red[0][0] + red[0][1] + red[0][2] + red[0][3]);
        atomicAdd(&accum[b * 3 + 1], red[1][0] + red[1][1] + red[1][2] + red[1][3]);
        atomicAdd(&accum[b * 3 + 2], red[2][0] + red[2][1] + red[2][2] + red[2][3]);
    }
}

// accum layout: [row r=0..4][b=0..3][3]; out cmp_loss [B=4][5][2]
__global__ void finalize_kernel(const float* __restrict__ accum,
                                float* __restrict__ out)
{
    int id = threadIdx.x;
    if (id < 20) {
        int b = id / 5;
        int r = id - b * 5;
        const float* a = accum + (size_t)(r * 4 + b) * 3;
        out[b * 10 + r * 2 + 0] = a[0] / (float)VOL;
        out[b * 10 + r * 2 + 1] = 1000.f * a[1] + a[2];
    }
}

extern "C" void kernel_launch(void* const* d_in, const int* in_sizes, int n_in,
                              void* d_out, int out_size, void* d_ws, size_t ws_size,
                              hipStream_t stream)
{
    const float* gt   = (const float*)d_in[0];
    const float* x0   = (const float*)d_in[1];
    const float* yobs = (const float*)d_in[2];
    const int*   mask = (const int*)d_in[3];
    const float* W1   = (const float*)d_in[4];
    const float* b1   = (const float*)d_in[5];
    const float* W2   = (const float*)d_in[6];
    const float* b2   = (const float*)d_in[7];
    // d_in[8..10]: Q COO (replaced by direct stencil); d_in[11]: n_fp (fixed 4)

    float* out_x    = (float*)d_out;
    float* out_loss = out_x + (size_t)BD * VOL;

    float* wsA   = (float*)d_ws;                    // one ping buffer (21 MB)
    float* accum = wsA + (size_t)BD * VOL;          // 60 floats [5][4][3]

    hipMemsetAsync(accum, 0, 60 * sizeof(float), stream);

    dim3 cgrid(VOL / 256, BD), cblock(256);
    dim3 pgrid(NXD / TS, NYD / TS, BD), pblock(256);

    // r0: cost(x0)
    cost_kernel<<<cgrid, cblock, 0, stream>>>(x0, gt, yobs, mask, accum + 0 * 12);
    // x1 = blend(phi(x0)) -> out_x
    phi_kernel<<<pgrid, pblock, 0, stream>>>(x0, W1, b1, W2, b2, yobs, mask, out_x, 1);
    cost_kernel<<<cgrid, cblock, 0, stream>>>(out_x, gt, yobs, mask, accum + 1 * 12);
    // x2 -> wsA
    phi_kernel<<<pgrid, pblock, 0, stream>>>(out_x, W1, b1, W2, b2, yobs, mask, wsA, 1);
    cost_kernel<<<cgrid, cblock, 0, stream>>>(wsA, gt, yobs, mask, accum + 2 * 12);
    // x3 -> out_x
    phi_kernel<<<pgrid, pblock, 0, stream>>>(wsA, W1, b1, W2, b2, yobs, mask, out_x, 1);
    cost_kernel<<<cgrid, cblock, 0, stream>>>(out_x, gt, yobs, mask, accum + 3 * 12);
    // x4 -> wsA
    phi_kernel<<<pgrid, pblock, 0, stream>>>(out_x, W1, b1, W2, b2, yobs, mask, wsA, 1);
    // x5 = phi(x4), no blend -> out_x (final output)
    phi_kernel<<<pgrid, pblock, 0, stream>>>(wsA, W1, b1, W2, b2, yobs, mask, out_x, 0);
    cost_kernel<<<cgrid, cblock, 0, stream>>>(out_x, gt, yobs, mask, accum + 4 * 12);

    finalize_kernel<<<dim3(1), dim3(64), 0, stream>>>(accum, out_loss);
}

// Round 2
// 2588.918 us; speedup vs baseline: 2.3563x; 2.3563x over previous
//
#include <hip/hip_runtime.h>

#define NXD 512
#define NYD 512
#define TD 5
#define BD 4
#define HIDD 64
#define PLANE (NXD*NYD)      /* 262144 */
#define VOL (TD*PLANE)       /* 1310720 */
#define TS 16
#define CBLK 256             /* cost blocks per batch */

// ---------------------------------------------------------------------------
// Fused phi_r: conv1(5->64,3x3,SAME) + bias + relu + conv2(64->5,3x3,SAME) +
// bias, then optional blend x_new = mask ? yobs : o.  (unchanged this round)
// ---------------------------------------------------------------------------
__global__ __launch_bounds__(256, 2)
void phi_kernel(const float* __restrict__ xin,
                const float* __restrict__ W1, const float* __restrict__ b1,
                const float* __restrict__ W2, const float* __restrict__ b2,
                const float* __restrict__ yobs, const int* __restrict__ mask,
                float* __restrict__ xout, int blend)
{
    __shared__ float sx[TD][20][20];     // 2000 floats
    __shared__ float sh[16][18][18];     // 5184 floats

    const int tid = threadIdx.x;
    const int b   = blockIdx.z;
    const int gx0 = blockIdx.x * TS;     // NX (H) tile origin
    const int gy0 = blockIdx.y * TS;     // NY (W) tile origin
    const float* xb = xin + (size_t)b * VOL;

    // ---- stage x tile (with halo 2), zero-padded ----
    for (int idx = tid; idx < TD * 400; idx += 256) {
        int c   = idx / 400;
        int rem = idx - c * 400;
        int u   = rem / 20;
        int v   = rem - u * 20;
        int gx  = gx0 + u - 2;
        int gy  = gy0 + v - 2;
        float val = 0.f;
        if (gx >= 0 && gx < NXD && gy >= 0 && gy < NYD)
            val = xb[c * PLANE + gx * NYD + gy];
        sx[c][u][v] = val;
    }

    float acc[TD] = {0.f, 0.f, 0.f, 0.f, 0.f};
    const int ti = tid >> 4;
    const int tj = tid & 15;

    for (int chunk = 0; chunk < 4; ++chunk) {
        const int c0 = chunk * 16;
        __syncthreads();  // sx ready (chunk 0) / sh reads of prev chunk done

        // ---- conv1: h over 18x18 region for 16 channels ----
        for (int pos = tid; pos < 324; pos += 256) {
            int i = pos / 18;
            int j = pos - i * 18;
            float xr[45];
            #pragma unroll
            for (int ci = 0; ci < 5; ++ci) {
                #pragma unroll
                for (int d = 0; d < 9; ++d)
                    xr[ci * 9 + d] = sx[ci][i + d / 3][j + d % 3];
            }
            #pragma unroll 4
            for (int c = 0; c < 16; ++c) {
                const float* w = W1 + (size_t)(c0 + c) * 45;  // uniform addr
                float h = b1[c0 + c];
                #pragma unroll
                for (int k = 0; k < 45; ++k) h = fmaf(xr[k], w[k], h);
                sh[c][i][j] = fmaxf(h, 0.f);
            }
        }
        __syncthreads();

        // ---- conv2 partial: accumulate 16 channels into 5 outputs ----
        #pragma unroll 4
        for (int c = 0; c < 16; ++c) {
            float v[9];
            #pragma unroll
            for (int d = 0; d < 9; ++d)
                v[d] = sh[c][ti + d / 3][tj + d % 3];
            #pragma unroll
            for (int co = 0; co < TD; ++co) {
                const float* w = W2 + (size_t)(co * HIDD + c0 + c) * 9;  // uniform
                float a = acc[co];
                #pragma unroll
                for (int d = 0; d < 9; ++d) a = fmaf(v[d], w[d], a);
                acc[co] = a;
            }
        }
    }

    // ---- epilogue: bias + blend + store ----
    const int gx = gx0 + ti;
    const int gy = gy0 + tj;
    const size_t base = (size_t)b * VOL + (size_t)gx * NYD + gy;
    #pragma unroll
    for (int co = 0; co < TD; ++co) {
        float o = acc[co] + b2[co];
        size_t off = base + (size_t)co * PLANE;
        if (blend) {
            int m = mask[off];
            if (m) o = yobs[off];
        }
        xout[off] = o;
    }
}

// ---------------------------------------------------------------------------
// Cost reduction, atomic-free. Grid (CBLK, B). Each block writes one partial
// triple {mse, dy, q} to partial[(b*CBLK + bx)*3 + k].
//   q = 6.01 v^2 - 2 v (t+ + x+ + y+ neighbors)   (equivalent to x^T Q x)
// ---------------------------------------------------------------------------
__global__ __launch_bounds__(256)
void cost_kernel(const float* __restrict__ x, const float* __restrict__ gt,
                 const float* __restrict__ yobs, const int* __restrict__ mask,
                 float* __restrict__ partial)
{
    const int b  = blockIdx.y;
    const size_t bbase = (size_t)b * VOL;

    float mse = 0.f, dy = 0.f, q = 0.f;
    for (int idx = blockIdx.x * 256 + threadIdx.x; idx < VOL; idx += CBLK * 256) {
        const size_t gi = bbase + idx;
        const int t   = idx / PLANE;
        const int rem = idx - t * PLANE;
        const int i   = rem / NYD;
        const int j   = rem - i * NYD;

        const float v  = x[gi];
        const float g  = gt[gi];
        const float yo = yobs[gi];
        const int   m  = mask[gi];

        mse += (g - v) * (g - v);
        float d = v - yo;
        if (m) dy += d * d;
        float qq = 6.01f * v * v;
        if (t < TD - 1)  qq -= 2.f * v * x[gi + PLANE];
        if (i < NXD - 1) qq -= 2.f * v * x[gi + NYD];
        if (j < NYD - 1) qq -= 2.f * v * x[gi + 1];
        q += qq;
    }

    // butterfly wave(64) reduction
    #pragma unroll
    for (int off = 32; off > 0; off >>= 1) {
        mse += __shfl_xor(mse, off, 64);
        dy  += __shfl_xor(dy,  off, 64);
        q   += __shfl_xor(q,   off, 64);
    }
    __shared__ float red[3][4];
    const int wave = threadIdx.x >> 6;
    const int lane = threadIdx.x & 63;
    if (lane == 0) { red[0][wave] = mse; red[1][wave] = dy; red[2][wave] = q; }
    __syncthreads();
    if (threadIdx.x == 0) {
        float* p = partial + (size_t)(b * CBLK + blockIdx.x) * 3;
        p[0] = red[0][0] + red[0][1] + red[0][2] + red[0][3];
        p[1] = red[1][0] + red[1][1] + red[1][2] + red[1][3];
        p[2] = red[2][0] + red[2][1] + red[2][2] + red[2][3];
    }
}

// partial layout: row r in [0,5): base = r * (BD*CBLK*3).
// out cmp_loss [B=4][5][2]. One block (256 thr) per (r,b) pair.
__global__ __launch_bounds__(256)
void finalize_kernel(const float* __restrict__ partial,
                     float* __restrict__ out)
{
    const int r = blockIdx.x / BD;
    const int b = blockIdx.x - r * BD;
    const float* base = partial + (size_t)r * (BD * CBLK * 3)
                                + (size_t)b * CBLK * 3;
    const float* p = base + (size_t)threadIdx.x * 3;
    float mse = p[0], dy = p[1], q = p[2];
    #pragma unroll
    for (int off = 32; off > 0; off >>= 1) {
        mse += __shfl_xor(mse, off, 64);
        dy  += __shfl_xor(dy,  off, 64);
        q   += __shfl_xor(q,   off, 64);
    }
    __shared__ float red[3][4];
    const int wave = threadIdx.x >> 6;
    const int lane = threadIdx.x & 63;
    if (lane == 0) { red[0][wave] = mse; red[1][wave] = dy; red[2][wave] = q; }
    __syncthreads();
    if (threadIdx.x == 0) {
        float m = red[0][0] + red[0][1] + red[0][2] + red[0][3];
        float d = red[1][0] + red[1][1] + red[1][2] + red[1][3];
        float qq = red[2][0] + red[2][1] + red[2][2] + red[2][3];
        out[b * 10 + r * 2 + 0] = m / (float)VOL;
        out[b * 10 + r * 2 + 1] = 1000.f * d + qq;
    }
}

extern "C" void kernel_launch(void* const* d_in, const int* in_sizes, int n_in,
                              void* d_out, int out_size, void* d_ws, size_t ws_size,
                              hipStream_t stream)
{
    const float* gt   = (const float*)d_in[0];
    const float* x0   = (const float*)d_in[1];
    const float* yobs = (const float*)d_in[2];
    const int*   mask = (const int*)d_in[3];
    const float* W1   = (const float*)d_in[4];
    const float* b1   = (const float*)d_in[5];
    const float* W2   = (const float*)d_in[6];
    const float* b2   = (const float*)d_in[7];

    float* out_x    = (float*)d_out;
    float* out_loss = out_x + (size_t)BD * VOL;

    float* wsA     = (float*)d_ws;                  // ping buffer (21 MB)
    float* partial = wsA + (size_t)BD * VOL;        // 5*4*CBLK*3 floats (15360)
    const size_t PROW = (size_t)BD * CBLK * 3;      // per-row partial stride

    dim3 cgrid(CBLK, BD), cblock(256);
    dim3 pgrid(NXD / TS, NYD / TS, BD), pblock(256);

    // r0: cost(x0)
    cost_kernel<<<cgrid, cblock, 0, stream>>>(x0, gt, yobs, mask, partial + 0 * PROW);
    // x1 = blend(phi(x0)) -> out_x
    phi_kernel<<<pgrid, pblock, 0, stream>>>(x0, W1, b1, W2, b2, yobs, mask, out_x, 1);
    cost_kernel<<<cgrid, cblock, 0, stream>>>(out_x, gt, yobs, mask, partial + 1 * PROW);
    // x2 -> wsA
    phi_kernel<<<pgrid, pblock, 0, stream>>>(out_x, W1, b1, W2, b2, yobs, mask, wsA, 1);
    cost_kernel<<<cgrid, cblock, 0, stream>>>(wsA, gt, yobs, mask, partial + 2 * PROW);
    // x3 -> out_x
    phi_kernel<<<pgrid, pblock, 0, stream>>>(wsA, W1, b1, W2, b2, yobs, mask, out_x, 1);
    cost_kernel<<<cgrid, cblock, 0, stream>>>(out_x, gt, yobs, mask, partial + 3 * PROW);
    // x4 -> wsA
    phi_kernel<<<pgrid, pblock, 0, stream>>>(out_x, W1, b1, W2, b2, yobs, mask, wsA, 1);
    // x5 = phi(x4), no blend -> out_x (final output)
    phi_kernel<<<pgrid, pblock, 0, stream>>>(wsA, W1, b1, W2, b2, yobs, mask, out_x, 0);
    cost_kernel<<<cgrid, cblock, 0, stream>>>(out_x, gt, yobs, mask, partial + 4 * PROW);

    finalize_kernel<<<dim3(5 * BD), dim3(256), 0, stream>>>(partial, out_loss);
}

// Round 3
// 1011.420 us; speedup vs baseline: 6.0314x; 2.5597x over previous
//
#include <hip/hip_runtime.h>
#include <hip/hip_bf16.h>

#define NXD 512
#define NYD 512
#define TD 5
#define BD 4
#define HIDD 64
#define PLANE (NXD*NYD)      /* 262144 */
#define VOL (TD*PLANE)       /* 1310720 */
#define CBLK 256             /* cost blocks per batch */

typedef __bf16 bf16x8 __attribute__((ext_vector_type(8)));
typedef float  f32x4  __attribute__((ext_vector_type(4)));

// LDS layouts (byte strides chosen for 16B alignment + odd 16B-group stride)
#define SX_PS   32           /* x tile: 8 bf16 (5 real+3 zero) = 16B + 16B pad */
#define SX_ROWS 24           /* 20 real + 4 pad rows read by padded m-tiles */
#define SX_COLS 20
#define SH_PS   144          /* h: 64 bf16 = 128B + 16B pad (stride 9 groups) */

// W1r: [kt=3][n=64][32 bf16]  k = tap*8 + c8  (tap 0..8 real, 9..11 zero)
// W2r: [kt=18][n=16][32 bf16] k = tap*64 + c64 (n 0..4 real, 5..15 zero)
#define W1R_ELEMS (3*64*32)   /* 6144 */
#define W2R_ELEMS (18*16*32)  /* 9216 */

__global__ __launch_bounds__(256)
void prep_weights(const float* __restrict__ W1, const float* __restrict__ W2,
                  __bf16* __restrict__ W1r, __bf16* __restrict__ W2r)
{
    int id = blockIdx.x * 256 + threadIdx.x;
    if (id < W1R_ELEMS) {
        int kt = id >> 11;            // /(64*32)
        int rem = id & 2047;
        int n = rem >> 5;
        int kk = rem & 31;
        int k = kt * 32 + kk;
        int tap = k >> 3, c = k & 7;
        float v = 0.f;
        if (tap <= 8 && c < 5)
            v = W1[(n * 5 + c) * 9 + tap];   // W1 [64][5][3][3]
        W1r[id] = (__bf16)v;
    } else if (id < W1R_ELEMS + W2R_ELEMS) {
        int id2 = id - W1R_ELEMS;
        int kt = id2 >> 9;            // /(16*32)
        int rem = id2 & 511;
        int n = rem >> 5;
        int kk = rem & 31;
        int k = kt * 32 + kk;
        int tap = k >> 6, c = k & 63;
        float v = 0.f;
        if (n < 5)
            v = W2[(n * 64 + c) * 9 + tap];  // W2 [5][64][3][3]
        W2r[id2] = (__bf16)v;
    }
}

// ---------------------------------------------------------------------------
// Fused phi via MFMA implicit GEMM.
// Block: 256 thr (4 waves), one 16x16 output tile, all channels.
// conv1: M = 18x18 h-region (padded to 384 = 24 m-tiles), N = 64, K = 96
//        (12 taps x 8ch; taps 9..11 have zero B). 3 K-MFMAs per (m,n).
// conv2: M = 256 out pixels (16 m-tiles), N = 16 (5 real), K = 576
//        (9 taps x 64 ch) = 18 K-MFMAs.
// ---------------------------------------------------------------------------
__global__ __launch_bounds__(256)
void phi_mfma(const float* __restrict__ xin,
              const __bf16* __restrict__ W1r, const __bf16* __restrict__ W2r,
              const float* __restrict__ b1, const float* __restrict__ b2,
              const float* __restrict__ yobs, const int* __restrict__ mask,
              float* __restrict__ xout, int blend)
{
    __shared__ __align__(16) char sx[SX_ROWS * SX_COLS * SX_PS];  // 15360 B
    __shared__ __align__(16) char sh[18 * 18 * SH_PS];            // 46656 B

    const int tid   = threadIdx.x;
    const int wv    = tid >> 6;
    const int lane  = tid & 63;
    const int l15   = lane & 15;
    const int quad  = lane >> 4;
    const int b     = blockIdx.z;
    const int gx0   = blockIdx.x * 16;
    const int gy0   = blockIdx.y * 16;
    const float* xb = xin + (size_t)b * VOL;

    // ---- zero sx (pad rows + pad channels must be 0) ----
    for (int i = tid; i < (SX_ROWS * SX_COLS * SX_PS) / 16; i += 256)
        ((f32x4*)sx)[i] = (f32x4){0.f, 0.f, 0.f, 0.f};
    __syncthreads();

    // ---- stage x tile 20x20 (halo 2), channel-interleaved bf16 ----
    for (int idx = tid; idx < TD * 400; idx += 256) {
        int c   = idx / 400;
        int rem = idx - c * 400;
        int u   = rem / 20;
        int v   = rem - u * 20;
        int gx  = gx0 + u - 2;
        int gy  = gy0 + v - 2;
        float val = 0.f;
        if (gx >= 0 && gx < NXD && gy >= 0 && gy < NYD)
            val = xb[c * PLANE + gx * NYD + gy];
        *(__bf16*)(sx + (u * 20 + v) * SX_PS + c * 2) = (__bf16)val;
    }

    // ---- preload conv1 B fragments (12 = 4 n-tiles x 3 k-tiles) ----
    bf16x8 B1[12];
    #pragma unroll
    for (int nt = 0; nt < 4; ++nt)
        #pragma unroll
        for (int kt = 0; kt < 3; ++kt)
            B1[nt * 3 + kt] = *(const bf16x8*)(W1r +
                ((size_t)(kt * 64 + nt * 16 + l15) * 32 + quad * 8));

    __syncthreads();

    // ---- conv1: each wave does 6 m-tiles ----
    for (int mi = 0; mi < 6; ++mi) {
        const int mt = wv * 6 + mi;
        const int p  = mt * 16 + l15;       // pixel in padded 24x16 m space
        const int i  = p / 18;
        const int j  = p - 18 * i;
        bf16x8 A[3];
        #pragma unroll
        for (int kt = 0; kt < 3; ++kt) {
            int tap = kt * 4 + quad;
            if (tap > 8) tap = 8;           // pad taps: B is zero, clamp addr
            const int u = i + tap / 3;      // i + ty + 1, ty in {-1,0,1}
            const int v = j + tap % 3;
            A[kt] = *(const bf16x8*)(sx + (u * 20 + v) * SX_PS);
        }
        #pragma unroll
        for (int nt = 0; nt < 4; ++nt) {
            f32x4 acc = {0.f, 0.f, 0.f, 0.f};
            #pragma unroll
            for (int kt = 0; kt < 3; ++kt)
                acc = __builtin_amdgcn_mfma_f32_16x16x32_bf16(
                          A[kt], B1[nt * 3 + kt], acc, 0, 0, 0);
            const int ch  = nt * 16 + l15;  // D col = channel
            const float bb = b1[ch];
            #pragma unroll
            for (int r = 0; r < 4; ++r) {   // D row = pixel quad*4+r
                const int pp = mt * 16 + quad * 4 + r;
                if (pp < 324) {
                    const int ii = pp / 18;
                    const int jj = pp - 18 * ii;
                    const float h = fmaxf(acc[r] + bb, 0.f);
                    *(__bf16*)(sh + (ii * 18 + jj) * SH_PS + ch * 2) = (__bf16)h;
                }
            }
        }
    }
    __syncthreads();

    // ---- conv2: each wave does 4 m-tiles, stream B per k-tile ----
    f32x4 acc2[4] = {{0.f,0.f,0.f,0.f},{0.f,0.f,0.f,0.f},
                     {0.f,0.f,0.f,0.f},{0.f,0.f,0.f,0.f}};
    int abase[4];
    #pragma unroll
    for (int m = 0; m < 4; ++m) {
        const int p2 = (wv * 4 + m) * 16 + l15;
        const int ti = p2 >> 4, tj = p2 & 15;
        abase[m] = (ti * 18 + tj) * SH_PS + quad * 16;  // +tap offset later
    }
    for (int kt = 0; kt < 18; ++kt) {
        const bf16x8 B = *(const bf16x8*)(W2r +
            ((size_t)(kt * 16 + l15) * 32 + quad * 8));
        const int tap  = kt >> 1;
        const int half = kt & 1;
        const int toff = (tap / 3 * 18 + tap % 3) * SH_PS + half * 64;
        #pragma unroll
        for (int m = 0; m < 4; ++m) {
            const bf16x8 A = *(const bf16x8*)(sh + abase[m] + toff);
            acc2[m] = __builtin_amdgcn_mfma_f32_16x16x32_bf16(A, B, acc2[m], 0, 0, 0);
        }
    }

    // ---- epilogue: bias + blend + store (only lanes with channel < 5) ----
    if (l15 < TD) {
        const float bias = b2[l15];
        const size_t bbase = (size_t)b * VOL + (size_t)l15 * PLANE;
        #pragma unroll
        for (int m = 0; m < 4; ++m) {
            #pragma unroll
            for (int r = 0; r < 4; ++r) {
                const int p2 = (wv * 4 + m) * 16 + quad * 4 + r;
                const int ti = p2 >> 4, tj = p2 & 15;
                const size_t off = bbase + (size_t)(gx0 + ti) * NYD + (gy0 + tj);
                float o = acc2[m][r] + bias;
                if (blend && mask[off]) o = yobs[off];
                xout[off] = o;
            }
        }
    }
}

// ---------------------------------------------------------------------------
// Cost reduction (unchanged from round 2)
// ---------------------------------------------------------------------------
__global__ __launch_bounds__(256)
void cost_kernel(const float* __restrict__ x, const float* __restrict__ gt,
                 const float* __restrict__ yobs, const int* __restrict__ mask,
                 float* __restrict__ partial)
{
    const int b  = blockIdx.y;
    const size_t bbase = (size_t)b * VOL;

    float mse = 0.f, dy = 0.f, q = 0.f;
    for (int idx = blockIdx.x * 256 + threadIdx.x; idx < VOL; idx += CBLK * 256) {
        const size_t gi = bbase + idx;
        const int t   = idx / PLANE;
        const int rem = idx - t * PLANE;
        const int i   = rem / NYD;
        const int j   = rem - i * NYD;

        const float v  = x[gi];
        const float g  = gt[gi];
        const float yo = yobs[gi];
        const int   m  = mask[gi];

        mse += (g - v) * (g - v);
        float d = v - yo;
        if (m) dy += d * d;
        float qq = 6.01f * v * v;
        if (t < TD - 1)  qq -= 2.f * v * x[gi + PLANE];
        if (i < NXD - 1) qq -= 2.f * v * x[gi + NYD];
        if (j < NYD - 1) qq -= 2.f * v * x[gi + 1];
        q += qq;
    }

    #pragma unroll
    for (int off = 32; off > 0; off >>= 1) {
        mse += __shfl_xor(mse, off, 64);
        dy  += __shfl_xor(dy,  off, 64);
        q   += __shfl_xor(q,   off, 64);
    }
    __shared__ float red[3][4];
    const int wave = threadIdx.x >> 6;
    const int lane = threadIdx.x & 63;
    if (lane == 0) { red[0][wave] = mse; red[1][wave] = dy; red[2][wave] = q; }
    __syncthreads();
    if (threadIdx.x == 0) {
        float* p = partial + (size_t)(b * CBLK + blockIdx.x) * 3;
        p[0] = red[0][0] + red[0][1] + red[0][2] + red[0][3];
        p[1] = red[1][0] + red[1][1] + red[1][2] + red[1][3];
        p[2] = red[2][0] + red[2][1] + red[2][2] + red[2][3];
    }
}

__global__ __launch_bounds__(256)
void finalize_kernel(const float* __restrict__ partial,
                     float* __restrict__ out)
{
    const int r = blockIdx.x / BD;
    const int b = blockIdx.x - r * BD;
    const float* p = partial + (size_t)r * (BD * CBLK * 3)
                             + (size_t)b * CBLK * 3 + (size_t)threadIdx.x * 3;
    float mse = p[0], dy = p[1], q = p[2];
    #pragma unroll
    for (int off = 32; off > 0; off >>= 1) {
        mse += __shfl_xor(mse, off, 64);
        dy  += __shfl_xor(dy,  off, 64);
        q   += __shfl_xor(q,   off, 64);
    }
    __shared__ float red[3][4];
    const int wave = threadIdx.x >> 6;
    const int lane = threadIdx.x & 63;
    if (lane == 0) { red[0][wave] = mse; red[1][wave] = dy; red[2][wave] = q; }
    __syncthreads();
    if (threadIdx.x == 0) {
        float m  = red[0][0] + red[0][1] + red[0][2] + red[0][3];
        float d  = red[1][0] + red[1][1] + red[1][2] + red[1][3];
        float qq = red[2][0] + red[2][1] + red[2][2] + red[2][3];
        out[b * 10 + r * 2 + 0] = m / (float)VOL;
        out[b * 10 + r * 2 + 1] = 1000.f * d + qq;
    }
}

extern "C" void kernel_launch(void* const* d_in, const int* in_sizes, int n_in,
                              void* d_out, int out_size, void* d_ws, size_t ws_size,
                              hipStream_t stream)
{
    const float* gt   = (const float*)d_in[0];
    const float* x0   = (const float*)d_in[1];
    const float* yobs = (const float*)d_in[2];
    const int*   mask = (const int*)d_in[3];
    const float* W1   = (const float*)d_in[4];
    const float* b1   = (const float*)d_in[5];
    const float* W2   = (const float*)d_in[6];
    const float* b2   = (const float*)d_in[7];

    float* out_x    = (float*)d_out;
    float* out_loss = out_x + (size_t)BD * VOL;

    float* wsA      = (float*)d_ws;                 // ping buffer (21 MB)
    float* partial  = wsA + (size_t)BD * VOL;       // 5*4*CBLK*3 f32
    __bf16* W1r     = (__bf16*)(partial + 5 * BD * CBLK * 3);
    __bf16* W2r     = W1r + W1R_ELEMS;
    const size_t PROW = (size_t)BD * CBLK * 3;

    dim3 cgrid(CBLK, BD), cblock(256);
    dim3 pgrid(NXD / 16, NYD / 16, BD), pblock(256);

    prep_weights<<<dim3(60), dim3(256), 0, stream>>>(W1, W2, W1r, W2r);

    cost_kernel<<<cgrid, cblock, 0, stream>>>(x0, gt, yobs, mask, partial + 0 * PROW);
    phi_mfma<<<pgrid, pblock, 0, stream>>>(x0, W1r, W2r, b1, b2, yobs, mask, out_x, 1);
    cost_kernel<<<cgrid, cblock, 0, stream>>>(out_x, gt, yobs, mask, partial + 1 * PROW);
    phi_mfma<<<pgrid, pblock, 0, stream>>>(out_x, W1r, W2r, b1, b2, yobs, mask, wsA, 1);
    cost_kernel<<<cgrid, cblock, 0, stream>>>(wsA, gt, yobs, mask, partial + 2 * PROW);
    phi_mfma<<<pgrid, pblock, 0, stream>>>(wsA, W1r, W2r, b1, b2, yobs, mask, out_x, 1);
    cost_kernel<<<cgrid, cblock, 0, stream>>>(out_x, gt, yobs, mask, partial + 3 * PROW);
    phi_mfma<<<pgrid, pblock, 0, stream>>>(out_x, W1r, W2r, b1, b2, yobs, mask, wsA, 1);
    phi_mfma<<<pgrid, pblock, 0, stream>>>(wsA, W1r, W2r, b1, b2, yobs, mask, out_x, 0);
    cost_kernel<<<cgrid, cblock, 0, stream>>>(out_x, gt, yobs, mask, partial + 4 * PROW);

    finalize_kernel<<<dim3(5 * BD), dim3(256), 0, stream>>>(partial, out_loss);
}

// Round 4
// 728.918 us; speedup vs baseline: 8.3689x; 1.3876x over previous
//
#include <hip/hip_runtime.h>
#include <hip/hip_bf16.h>

#define NXD 512
#define NYD 512
#define TD 5
#define BD 4
#define HIDD 64
#define PLANE (NXD*NYD)      /* 262144 */
#define VOL (TD*PLANE)       /* 1310720 */
#define CBLK 256             /* cost blocks per batch */

typedef __bf16 bf16x8 __attribute__((ext_vector_type(8)));
typedef float  f32x4  __attribute__((ext_vector_type(4)));

// LDS strides: sx 16 B/pixel (group stride 1), sh 80 B/pixel (group stride 5,
// coprime with 8 -> conflict-free ds_read_b128 across lanes).
#define SX_PS 16
#define SH_PS 80

// W1r: [kt=3][n=64][32 bf16]   k = tap*8 + c8   (taps 9..11 zero-padded)
// W2r: [h=2][tap=9][n=16][32]  k(within half) = tap*32 + c32; n 5..15 zero
#define W1R_ELEMS (3*64*32)   /* 6144 */
#define W2R_ELEMS (2*9*16*32) /* 9216 */

__global__ __launch_bounds__(256)
void prep_weights(const float* __restrict__ W1, const float* __restrict__ W2,
                  __bf16* __restrict__ W1r, __bf16* __restrict__ W2r)
{
    int id = blockIdx.x * 256 + threadIdx.x;
    if (id < W1R_ELEMS) {
        int kt  = id >> 11;           // /(64*32)
        int rem = id & 2047;
        int n   = rem >> 5;
        int kk  = rem & 31;
        int k   = kt * 32 + kk;
        int tap = k >> 3, c = k & 7;
        float v = 0.f;
        if (tap <= 8 && c < 5)
            v = W1[(n * 5 + c) * 9 + tap];      // W1 [64][5][3][3]
        W1r[id] = (__bf16)v;
    } else if (id < W1R_ELEMS + W2R_ELEMS) {
        int id2 = id - W1R_ELEMS;
        int h    = id2 / 4608;
        int rem  = id2 - h * 4608;
        int tap  = rem >> 9;          // /(16*32)
        int rem2 = rem & 511;
        int n    = rem2 >> 5;
        int c    = rem2 & 31;
        float v = 0.f;
        if (n < 5)
            v = W2[(n * HIDD + h * 32 + c) * 9 + tap];  // W2 [5][64][3][3]
        W2r[id2] = (__bf16)v;
    }
}

// ---------------------------------------------------------------------------
// Fused phi via MFMA implicit GEMM, half-channel pipelined to fit 4 blocks/CU.
// Block: 256 thr (4 waves), one 16x16 output tile.
// Per half (32 hidden ch):
//   conv1: M=384 (24 m-tiles, 324 real), N=32 (2 n-tiles), K=96 (3 k-tiles)
//   conv2: K=288 (9 taps x 32ch) = 9 MFMAs per m-tile, acc persists.
// ---------------------------------------------------------------------------
__global__ __launch_bounds__(256, 4)
void phi_mfma(const float* __restrict__ xin,
              const __bf16* __restrict__ W1r, const __bf16* __restrict__ W2r,
              const float* __restrict__ b1, const float* __restrict__ b2,
              const float* __restrict__ yobs, const int* __restrict__ mask,
              float* __restrict__ xout, int blend)
{
    __shared__ __align__(16) char sx[24 * 20 * SX_PS];  // 7680 B
    __shared__ __align__(16) char sh[324 * SH_PS];      // 25920 B

    const int tid   = threadIdx.x;
    const int wv    = tid >> 6;
    const int lane  = tid & 63;
    const int l15   = lane & 15;
    const int quad  = lane >> 4;
    const int b     = blockIdx.z;
    const int gx0   = blockIdx.x * 16;
    const int gy0   = blockIdx.y * 16;
    const float* xb = xin + (size_t)b * VOL;

    // ---- stage x tile 20x20 (halo 2): one b128 write per pixel ----
    for (int p = tid; p < 400; p += 256) {
        const int u  = p / 20;
        const int v  = p - u * 20;
        const int gx = gx0 + u - 2;
        const int gy = gy0 + v - 2;
        bf16x8 pix = {(__bf16)0.f,(__bf16)0.f,(__bf16)0.f,(__bf16)0.f,
                      (__bf16)0.f,(__bf16)0.f,(__bf16)0.f,(__bf16)0.f};
        if (gx >= 0 && gx < NXD && gy >= 0 && gy < NYD) {
            const float* src = xb + (size_t)gx * NYD + gy;
            #pragma unroll
            for (int c = 0; c < TD; ++c) pix[c] = (__bf16)src[(size_t)c * PLANE];
        }
        *(bf16x8*)(sx + p * SX_PS) = pix;
    }

    f32x4 acc2[4] = {{0.f,0.f,0.f,0.f},{0.f,0.f,0.f,0.f},
                     {0.f,0.f,0.f,0.f},{0.f,0.f,0.f,0.f}};
    int abase[4];
    #pragma unroll
    for (int m = 0; m < 4; ++m) {
        const int p2 = (wv * 4 + m) * 16 + l15;
        const int ti = p2 >> 4, tj = p2 & 15;
        abase[m] = (ti * 18 + tj) * SH_PS + quad * 16;
    }

    for (int half = 0; half < 2; ++half) {
        // ---- conv1 B fragments for this half (2 n-tiles x 3 k-tiles) ----
        bf16x8 B1[2][3];
        #pragma unroll
        for (int nt = 0; nt < 2; ++nt)
            #pragma unroll
            for (int kt = 0; kt < 3; ++kt)
                B1[nt][kt] = *(const bf16x8*)(W1r +
                    ((size_t)(kt * 64 + (half * 2 + nt) * 16 + l15) * 32 + quad * 8));

        __syncthreads();  // staging done (half0) / prev conv2 reads done (half1)

        // ---- conv1: each wave 6 m-tiles ----
        for (int mi = 0; mi < 6; ++mi) {
            const int mt = wv * 6 + mi;
            const int p  = mt * 16 + l15;     // pixel in padded 384-m space
            const int i  = p / 18;
            const int j  = p - 18 * i;
            bf16x8 A[3];
            #pragma unroll
            for (int kt = 0; kt < 3; ++kt) {
                int tap = kt * 4 + quad;
                if (tap > 8) tap = 8;         // pad taps: B is zero, clamp addr
                const int u = i + tap / 3;
                const int v = j + tap % 3;
                A[kt] = *(const bf16x8*)(sx + (u * 20 + v) * SX_PS);
            }
            #pragma unroll
            for (int nt = 0; nt < 2; ++nt) {
                f32x4 acc = {0.f, 0.f, 0.f, 0.f};
                #pragma unroll
                for (int kt = 0; kt < 3; ++kt)
                    acc = __builtin_amdgcn_mfma_f32_16x16x32_bf16(
                              A[kt], B1[nt][kt], acc, 0, 0, 0);
                const int chl = nt * 16 + l15;        // channel within half
                const float bb = b1[half * 32 + chl];
                #pragma unroll
                for (int r = 0; r < 4; ++r) {
                    const int pp = mt * 16 + quad * 4 + r;
                    if (pp < 324) {
                        const float h = fmaxf(acc[r] + bb, 0.f);
                        *(__bf16*)(sh + pp * SH_PS + chl * 2) = (__bf16)h;
                    }
                }
            }
        }
        __syncthreads();

        // ---- conv2: 9 taps of this half ----
        #pragma unroll 3
        for (int tap = 0; tap < 9; ++tap) {
            const bf16x8 B = *(const bf16x8*)(W2r +
                ((size_t)((half * 9 + tap) * 16 + l15) * 32 + quad * 8));
            const int toff = (tap / 3 * 18 + tap % 3) * SH_PS;
            #pragma unroll
            for (int m = 0; m < 4; ++m) {
                const bf16x8 A = *(const bf16x8*)(sh + abase[m] + toff);
                acc2[m] = __builtin_amdgcn_mfma_f32_16x16x32_bf16(A, B, acc2[m], 0, 0, 0);
            }
        }
    }

    // ---- epilogue: bias + blend + store (lanes with channel < 5) ----
    if (l15 < TD) {
        const float bias = b2[l15];
        const size_t bbase = (size_t)b * VOL + (size_t)l15 * PLANE;
        #pragma unroll
        for (int m = 0; m < 4; ++m) {
            #pragma unroll
            for (int r = 0; r < 4; ++r) {
                const int p2 = (wv * 4 + m) * 16 + quad * 4 + r;
                const int ti = p2 >> 4, tj = p2 & 15;
                const size_t off = bbase + (size_t)(gx0 + ti) * NYD + (gy0 + tj);
                float o = acc2[m][r] + bias;
                if (blend && mask[off]) o = yobs[off];
                xout[off] = o;
            }
        }
    }
}

// ---------------------------------------------------------------------------
// Cost reduction (unchanged)
// ---------------------------------------------------------------------------
__global__ __launch_bounds__(256)
void cost_kernel(const float* __restrict__ x, const float* __restrict__ gt,
                 const float* __restrict__ yobs, const int* __restrict__ mask,
                 float* __restrict__ partial)
{
    const int b  = blockIdx.y;
    const size_t bbase = (size_t)b * VOL;

    float mse = 0.f, dy = 0.f, q = 0.f;
    for (int idx = blockIdx.x * 256 + threadIdx.x; idx < VOL; idx += CBLK * 256) {
        const size_t gi = bbase + idx;
        const int t   = idx / PLANE;
        const int rem = idx - t * PLANE;
        const int i   = rem / NYD;
        const int j   = rem - i * NYD;

        const float v  = x[gi];
        const float g  = gt[gi];
        const float yo = yobs[gi];
        const int   m  = mask[gi];

        mse += (g - v) * (g - v);
        float d = v - yo;
        if (m) dy += d * d;
        float qq = 6.01f * v * v;
        if (t < TD - 1)  qq -= 2.f * v * x[gi + PLANE];
        if (i < NXD - 1) qq -= 2.f * v * x[gi + NYD];
        if (j < NYD - 1) qq -= 2.f * v * x[gi + 1];
        q += qq;
    }

    #pragma unroll
    for (int off = 32; off > 0; off >>= 1) {
        mse += __shfl_xor(mse, off, 64);
        dy  += __shfl_xor(dy,  off, 64);
        q   += __shfl_xor(q,   off, 64);
    }
    __shared__ float red[3][4];
    const int wave = threadIdx.x >> 6;
    const int lane = threadIdx.x & 63;
    if (lane == 0) { red[0][wave] = mse; red[1][wave] = dy; red[2][wave] = q; }
    __syncthreads();
    if (threadIdx.x == 0) {
        float* p = partial + (size_t)(b * CBLK + blockIdx.x) * 3;
        p[0] = red[0][0] + red[0][1] + red[0][2] + red[0][3];
        p[1] = red[1][0] + red[1][1] + red[1][2] + red[1][3];
        p[2] = red[2][0] + red[2][1] + red[2][2] + red[2][3];
    }
}

__global__ __launch_bounds__(256)
void finalize_kernel(const float* __restrict__ partial,
                     float* __restrict__ out)
{
    const int r = blockIdx.x / BD;
    const int b = blockIdx.x - r * BD;
    const float* p = partial + (size_t)r * (BD * CBLK * 3)
                             + (size_t)b * CBLK * 3 + (size_t)threadIdx.x * 3;
    float mse = p[0], dy = p[1], q = p[2];
    #pragma unroll
    for (int off = 32; off > 0; off >>= 1) {
        mse += __shfl_xor(mse, off, 64);
        dy  += __shfl_xor(dy,  off, 64);
        q   += __shfl_xor(q,   off, 64);
    }
    __shared__ float red[3][4];
    const int wave = threadIdx.x >> 6;
    const int lane = threadIdx.x & 63;
    if (lane == 0) { red[0][wave] = mse; red[1][wave] = dy; red[2][wave] = q; }
    __syncthreads();
    if (threadIdx.x == 0) {
        float m  = red[0][0] + red[0][1] + red[0][2] + red[0][3];
        float d  = red[1][0] + red[1][1] + red[1][2] + red[1][3];
        float qq = red[2][0] + red[2][1] + red[2][2] + red[2][3];
        out[b * 10 + r * 2 + 0] = m / (float)VOL;
        out[b * 10 + r * 2 + 1] = 1000.f * d + qq;
    }
}

extern "C" void kernel_launch(void* const* d_in, const int* in_sizes, int n_in,
                              void* d_out, int out_size, void* d_ws, size_t ws_size,
                              hipStream_t stream)
{
    const float* gt   = (const float*)d_in[0];
    const float* x0   = (const float*)d_in[1];
    const float* yobs = (const float*)d_in[2];
    const int*   mask = (const int*)d_in[3];
    const float* W1   = (const float*)d_in[4];
    const float* b1   = (const float*)d_in[5];
    const float* W2   = (const float*)d_in[6];
    const float* b2   = (const float*)d_in[7];

    float* out_x    = (float*)d_out;
    float* out_loss = out_x + (size_t)BD * VOL;

    float* wsA      = (float*)d_ws;                 // ping buffer (21 MB)
    float* partial  = wsA + (size_t)BD * VOL;       // 5*4*CBLK*3 f32
    __bf16* W1r     = (__bf16*)(partial + 5 * BD * CBLK * 3);
    __bf16* W2r     = W1r + W1R_ELEMS;
    const size_t PROW = (size_t)BD * CBLK * 3;

    dim3 cgrid(CBLK, BD), cblock(256);
    dim3 pgrid(NXD / 16, NYD / 16, BD), pblock(256);

    prep_weights<<<dim3(60), dim3(256), 0, stream>>>(W1, W2, W1r, W2r);

    cost_kernel<<<cgrid, cblock, 0, stream>>>(x0, gt, yobs, mask, partial + 0 * PROW);
    phi_mfma<<<pgrid, pblock, 0, stream>>>(x0, W1r, W2r, b1, b2, yobs, mask, out_x, 1);
    cost_kernel<<<cgrid, cblock, 0, stream>>>(out_x, gt, yobs, mask, partial + 1 * PROW);
    phi_mfma<<<pgrid, pblock, 0, stream>>>(out_x, W1r, W2r, b1, b2, yobs, mask, wsA, 1);
    cost_kernel<<<cgrid, cblock, 0, stream>>>(wsA, gt, yobs, mask, partial + 2 * PROW);
    phi_mfma<<<pgrid, pblock, 0, stream>>>(wsA, W1r, W2r, b1, b2, yobs, mask, out_x, 1);
    cost_kernel<<<cgrid, cblock, 0, stream>>>(out_x, gt, yobs, mask, partial + 3 * PROW);
    phi_mfma<<<pgrid, pblock, 0, stream>>>(out_x, W1r, W2r, b1, b2, yobs, mask, wsA, 1);
    phi_mfma<<<pgrid, pblock, 0, stream>>>(wsA, W1r, W2r, b1, b2, yobs, mask, out_x, 0);
    cost_kernel<<<cgrid, cblock, 0, stream>>>(out_x, gt, yobs, mask, partial + 4 * PROW);

    finalize_kernel<<<dim3(5 * BD), dim3(256), 0, stream>>>(partial, out_loss);
}

// Round 5
// 575.364 us; speedup vs baseline: 10.6024x; 1.2669x over previous
//
#include <hip/hip_runtime.h>
#include <hip/hip_bf16.h>

#define NXD 512
#define NYD 512
#define TD 5
#define BD 4
#define HIDD 64
#define PLANE (NXD*NYD)      /* 262144 */
#define VOL (TD*PLANE)       /* 1310720 */
#define CBLK 1024            /* cost blocks per batch (matches phi grid) */

typedef __bf16 bf16x8 __attribute__((ext_vector_type(8)));
typedef __bf16 bf16x4 __attribute__((ext_vector_type(4)));
typedef float  f32x4  __attribute__((ext_vector_type(4)));

// LDS strides: sx 16 B/pixel; sh 80 B/pixel (group stride 5, coprime with 8).
#define SX_PS 16
#define SH_PS 80

// W1r: [kt=3][ch=64][32 bf16]   k = tap*8 + c8   (taps 9..11 zero-padded)
// W2r: [h=2][tap=9][out=16][32] k(within half) = c32; out 5..15 zero
#define W1R_ELEMS (3*64*32)   /* 6144 */
#define W2R_ELEMS (2*9*16*32) /* 9216 */

__global__ __launch_bounds__(256)
void prep_weights(const float* __restrict__ W1, const float* __restrict__ W2,
                  __bf16* __restrict__ W1r, __bf16* __restrict__ W2r)
{
    int id = blockIdx.x * 256 + threadIdx.x;
    if (id < W1R_ELEMS) {
        int kt  = id >> 11;
        int rem = id & 2047;
        int n   = rem >> 5;
        int kk  = rem & 31;
        int k   = kt * 32 + kk;
        int tap = k >> 3, c = k & 7;
        float v = 0.f;
        if (tap <= 8 && c < 5)
            v = W1[(n * 5 + c) * 9 + tap];      // W1 [64][5][3][3]
        W1r[id] = (__bf16)v;
    } else if (id < W1R_ELEMS + W2R_ELEMS) {
        int id2 = id - W1R_ELEMS;
        int h    = id2 / 4608;
        int rem  = id2 - h * 4608;
        int tap  = rem >> 9;
        int rem2 = rem & 511;
        int n    = rem2 >> 5;
        int c    = rem2 & 31;
        float v = 0.f;
        if (n < 5)
            v = W2[(n * HIDD + h * 32 + c) * 9 + tap];  // W2 [5][64][3][3]
        W2r[id2] = (__bf16)v;
    }
}

// ---------------------------------------------------------------------------
// Fused phi (+ optional cost of its INPUT tile).
// Swapped operand convention: A = weights (m = channel rows), B = activations
// (n = pixel cols).  D: row = quad*4+reg = channel, col = l15 = pixel.
// conv1 per half: M=32 ch (2 m-tiles), N=384 px (24 n-tiles), K=96 (3 kt).
//   -> h written as ONE b64 (4 ch) per (nt, mt) per lane.
// conv2 per half: M=16 out (5 real), N=16 px rows x 4, K=9 taps x 32 ch;
//   rolling 6-row x 3-shift register window: 18 b128 reads instead of 36.
// ---------------------------------------------------------------------------
__global__ __launch_bounds__(256, 4)
void phi_mfma(const float* __restrict__ xin,
              const __bf16* __restrict__ W1r, const __bf16* __restrict__ W2r,
              const float* __restrict__ b1, const float* __restrict__ b2,
              const float* __restrict__ gt, const float* __restrict__ yobs,
              const int* __restrict__ mask,
              float* __restrict__ xout, float* __restrict__ cpart, int blend)
{
    __shared__ __align__(16) char sx[24 * 20 * SX_PS];  // 7680 B
    __shared__ __align__(16) char sh[324 * SH_PS];      // 25920 B
    __shared__ float red[3][4];

    const int tid   = threadIdx.x;
    const int wv    = tid >> 6;
    const int lane  = tid & 63;
    const int l15   = lane & 15;
    const int quad  = lane >> 4;
    const int b     = blockIdx.z;
    const int gx0   = blockIdx.x * 16;
    const int gy0   = blockIdx.y * 16;
    const float* xb = xin + (size_t)b * VOL;

    // ---- stage x tile 20x20 (halo 2): one b128 write per pixel ----
    for (int p = tid; p < 400; p += 256) {
        const int u  = p / 20;
        const int v  = p - u * 20;
        const int gx = gx0 + u - 2;
        const int gy = gy0 + v - 2;
        bf16x8 pix = {(__bf16)0.f,(__bf16)0.f,(__bf16)0.f,(__bf16)0.f,
                      (__bf16)0.f,(__bf16)0.f,(__bf16)0.f,(__bf16)0.f};
        if (gx >= 0 && gx < NXD && gy >= 0 && gy < NYD) {
            const float* src = xb + (size_t)gx * NYD + gy;
            #pragma unroll
            for (int c = 0; c < TD; ++c) pix[c] = (__bf16)src[(size_t)c * PLANE];
        }
        *(bf16x8*)(sx + p * SX_PS) = pix;
    }
    __syncthreads();

    // ---- fused cost of the INPUT x (rows 0..3 of cmp_loss) ----
    if (cpart) {
        const int ti = tid >> 4, tj = tid & 15;
        const int u  = ti + 2,  v  = tj + 2;
        const size_t gbase = (size_t)b * VOL + (size_t)(gx0 + ti) * NYD + (gy0 + tj);
        float mse = 0.f, dy = 0.f, q = 0.f;
        #pragma unroll
        for (int c = 0; c < TD; ++c) {
            const size_t gi = gbase + (size_t)c * PLANE;
            const float vv = xin[gi];                 // fp32 (L2-hot)
            const float g  = gt[gi];
            const float yo = yobs[gi];
            const int   m  = mask[gi];
            mse += (g - vv) * (g - vv);
            float d = vv - yo;
            if (m) dy += d * d;
            // neighbors from bf16 tile (q is ~0.5% of the loss; bf16 is fine;
            // zero-halo makes boundary terms vanish automatically)
            float xp1 = (float)*(const __bf16*)(sx + (u * 20 + v + 1) * SX_PS + c * 2);
            float yp1 = (float)*(const __bf16*)(sx + ((u + 1) * 20 + v) * SX_PS + c * 2);
            float tp1 = (c < TD - 1)
                      ? (float)*(const __bf16*)(sx + (u * 20 + v) * SX_PS + (c + 1) * 2)
                      : 0.f;
            q += 6.01f * vv * vv - 2.f * vv * (xp1 + yp1 + tp1);
        }
        #pragma unroll
        for (int off = 32; off > 0; off >>= 1) {
            mse += __shfl_xor(mse, off, 64);
            dy  += __shfl_xor(dy,  off, 64);
            q   += __shfl_xor(q,   off, 64);
        }
        if (lane == 0) { red[0][wv] = mse; red[1][wv] = dy; red[2][wv] = q; }
        __syncthreads();
        if (tid == 0) {
            float* pp = cpart + ((size_t)b * 1024 + blockIdx.y * 32 + blockIdx.x) * 3;
            pp[0] = red[0][0] + red[0][1] + red[0][2] + red[0][3];
            pp[1] = red[1][0] + red[1][1] + red[1][2] + red[1][3];
            pp[2] = red[2][0] + red[2][1] + red[2][2] + red[2][3];
        }
    }

    f32x4 acc2[4] = {{0.f,0.f,0.f,0.f},{0.f,0.f,0.f,0.f},
                     {0.f,0.f,0.f,0.f},{0.f,0.f,0.f,0.f}};

    for (int half = 0; half < 2; ++half) {
        // ---- conv1 A (weight) frags + bias ----
        bf16x8 A1[2][3];
        f32x4  bias1[2];
        #pragma unroll
        for (int mt = 0; mt < 2; ++mt) {
            bias1[mt] = *(const f32x4*)(b1 + half * 32 + mt * 16 + quad * 4);
            #pragma unroll
            for (int kt = 0; kt < 3; ++kt)
                A1[mt][kt] = *(const bf16x8*)(W1r +
                    ((size_t)(kt * 64 + half * 32 + mt * 16 + l15) * 32 + quad * 8));
        }
        if (half) __syncthreads();   // prev conv2 reads of sh done

        // ---- conv1: 6 pixel n-tiles per wave ----
        #pragma unroll 2
        for (int nt = 0; nt < 6; ++nt) {
            const int ntg = wv * 6 + nt;
            const int p   = ntg * 16 + l15;   // pixel in padded 384 n-space
            const int i   = p / 18;
            const int j   = p - 18 * i;
            const int pb  = (i * 20 + j) * SX_PS;
            bf16x8 Bx[3];
            #pragma unroll
            for (int kt = 0; kt < 3; ++kt) {
                int tap = kt * 4 + quad;
                if (tap > 8) tap = 8;         // pad taps: weights zero, clamp addr
                Bx[kt] = *(const bf16x8*)(sx + pb + ((tap / 3) * 20 + tap % 3) * SX_PS);
            }
            #pragma unroll
            for (int mt = 0; mt < 2; ++mt) {
                f32x4 a = {0.f, 0.f, 0.f, 0.f};
                #pragma unroll
                for (int kt = 0; kt < 3; ++kt)
                    a = __builtin_amdgcn_mfma_f32_16x16x32_bf16(
                            A1[mt][kt], Bx[kt], a, 0, 0, 0);
                if (p < 324) {
                    bf16x4 hv;
                    #pragma unroll
                    for (int r = 0; r < 4; ++r)
                        hv[r] = (__bf16)fmaxf(a[r] + bias1[mt][r], 0.f);
                    *(bf16x4*)(sh + p * SH_PS + (mt * 16 + quad * 4) * 2) = hv;
                }
            }
        }
        __syncthreads();

        // ---- conv2: rolling 6-row x 3-shift window ----
        bf16x8 A2[9];
        #pragma unroll
        for (int tap = 0; tap < 9; ++tap)
            A2[tap] = *(const bf16x8*)(W2r +
                ((size_t)((half * 9 + tap) * 16 + l15) * 32 + quad * 8));

        const int shbase = (wv * 4 * 18 + l15) * SH_PS + quad * 16;
        bf16x8 R[6][3];
        #pragma unroll
        for (int rr = 0; rr < 3; ++rr)
            #pragma unroll
            for (int tx = 0; tx < 3; ++tx)
                R[rr][tx] = *(const bf16x8*)(sh + shbase + (rr * 18 + tx) * SH_PS);
        #pragma unroll
        for (int m = 0; m < 4; ++m) {
            #pragma unroll
            for (int dy = 0; dy < 3; ++dy)
                #pragma unroll
                for (int tx = 0; tx < 3; ++tx)
                    acc2[m] = __builtin_amdgcn_mfma_f32_16x16x32_bf16(
                                  A2[dy * 3 + tx], R[m + dy][tx], acc2[m], 0, 0, 0);
            if (m < 3) {
                #pragma unroll
                for (int tx = 0; tx < 3; ++tx)
                    R[m + 3][tx] = *(const bf16x8*)(sh + shbase +
                                                    ((m + 3) * 18 + tx) * SH_PS);
            }
        }
    }

    // ---- epilogue: D row = out-channel, col = pixel ----
    float b2v[4];
    #pragma unroll
    for (int r = 0; r < 4; ++r) {
        const int ch = quad * 4 + r;
        b2v[r] = (ch < TD) ? b2[ch] : 0.f;
    }
    #pragma unroll
    for (int m = 0; m < 4; ++m) {
        const int ti2 = wv * 4 + m;
        const size_t rowoff = (size_t)b * VOL + (size_t)(gx0 + ti2) * NYD + (gy0 + l15);
        #pragma unroll
        for (int r = 0; r < 4; ++r) {
            const int ch = quad * 4 + r;
            if (ch < TD) {
                const size_t off = rowoff + (size_t)ch * PLANE;
                float o = acc2[m][r] + b2v[r];
                if (blend && mask[off]) o = yobs[off];
                xout[off] = o;
            }
        }
    }
}

// ---------------------------------------------------------------------------
// Standalone cost (for x5 only). Grid (1024, BD); 5 elems/thread.
// ---------------------------------------------------------------------------
__global__ __launch_bounds__(256)
void cost_kernel(const float* __restrict__ x, const float* __restrict__ gt,
                 const float* __restrict__ yobs, const int* __restrict__ mask,
                 float* __restrict__ partial)
{
    const int b  = blockIdx.y;
    const size_t bbase = (size_t)b * VOL;

    float mse = 0.f, dy = 0.f, q = 0.f;
    for (int idx = blockIdx.x * 256 + threadIdx.x; idx < VOL; idx += CBLK * 256) {
        const size_t gi = bbase + idx;
        const int t   = idx / PLANE;
        const int rem = idx - t * PLANE;
        const int i   = rem / NYD;
        const int j   = rem - i * NYD;

        const float v  = x[gi];
        const float g  = gt[gi];
        const float yo = yobs[gi];
        const int   m  = mask[gi];

        mse += (g - v) * (g - v);
        float d = v - yo;
        if (m) dy += d * d;
        float qq = 6.01f * v * v;
        if (t < TD - 1)  qq -= 2.f * v * x[gi + PLANE];
        if (i < NXD - 1) qq -= 2.f * v * x[gi + NYD];
        if (j < NYD - 1) qq -= 2.f * v * x[gi + 1];
        q += qq;
    }

    #pragma unroll
    for (int off = 32; off > 0; off >>= 1) {
        mse += __shfl_xor(mse, off, 64);
        dy  += __shfl_xor(dy,  off, 64);
        q   += __shfl_xor(q,   off, 64);
    }
    __shared__ float red[3][4];
    const int wave = threadIdx.x >> 6;
    const int lane = threadIdx.x & 63;
    if (lane == 0) { red[0][wave] = mse; red[1][wave] = dy; red[2][wave] = q; }
    __syncthreads();
    if (threadIdx.x == 0) {
        float* p = partial + ((size_t)b * CBLK + blockIdx.x) * 3;
        p[0] = red[0][0] + red[0][1] + red[0][2] + red[0][3];
        p[1] = red[1][0] + red[1][1] + red[1][2] + red[1][3];
        p[2] = red[2][0] + red[2][1] + red[2][2] + red[2][3];
    }
}

// cpart layout: [row r=0..4][b=0..3][1024][3].  out cmp_loss [B=4][5][2].
__global__ __launch_bounds__(256)
void finalize_kernel(const float* __restrict__ cpart,
                     float* __restrict__ out)
{
    const int r = blockIdx.x / BD;
    const int b = blockIdx.x - r * BD;
    const float* base = cpart + ((size_t)r * BD + b) * 1024 * 3;
    float mse = 0.f, dy = 0.f, q = 0.f;
    for (int k = threadIdx.x; k < 1024; k += 256) {
        mse += base[k * 3 + 0];
        dy  += base[k * 3 + 1];
        q   += base[k * 3 + 2];
    }
    #pragma unroll
    for (int off = 32; off > 0; off >>= 1) {
        mse += __shfl_xor(mse, off, 64);
        dy  += __shfl_xor(dy,  off, 64);
        q   += __shfl_xor(q,   off, 64);
    }
    __shared__ float red[3][4];
    const int wave = threadIdx.x >> 6;
    const int lane = threadIdx.x & 63;
    if (lane == 0) { red[0][wave] = mse; red[1][wave] = dy; red[2][wave] = q; }
    __syncthreads();
    if (threadIdx.x == 0) {
        float m  = red[0][0] + red[0][1] + red[0][2] + red[0][3];
        float d  = red[1][0] + red[1][1] + red[1][2] + red[1][3];
        float qq = red[2][0] + red[2][1] + red[2][2] + red[2][3];
        out[b * 10 + r * 2 + 0] = m / (float)VOL;
        out[b * 10 + r * 2 + 1] = 1000.f * d + qq;
    }
}

extern "C" void kernel_launch(void* const* d_in, const int* in_sizes, int n_in,
                              void* d_out, int out_size, void* d_ws, size_t ws_size,
                              hipStream_t stream)
{
    const float* gt   = (const float*)d_in[0];
    const float* x0   = (const float*)d_in[1];
    const float* yobs = (const float*)d_in[2];
    const int*   mask = (const int*)d_in[3];
    const float* W1   = (const float*)d_in[4];
    const float* b1   = (const float*)d_in[5];
    const float* W2   = (const float*)d_in[6];
    const float* b2   = (const float*)d_in[7];

    float* out_x    = (float*)d_out;
    float* out_loss = out_x + (size_t)BD * VOL;

    float* wsA      = (float*)d_ws;                   // ping buffer (21 MB)
    float* cpart    = wsA + (size_t)BD * VOL;         // 5*4*1024*3 floats
    __bf16* W1r     = (__bf16*)(cpart + 5 * BD * 1024 * 3);
    __bf16* W2r     = W1r + W1R_ELEMS;
    const size_t PROW = (size_t)BD * 1024 * 3;        // per-row stride

    dim3 pgrid(NXD / 16, NYD / 16, BD), pblock(256);
    dim3 cgrid(CBLK, BD), cblock(256);

    prep_weights<<<dim3(60), dim3(256), 0, stream>>>(W1, W2, W1r, W2r);

    // x1..x4 blended, each phi also computes cost of its INPUT (rows 0..3)
    phi_mfma<<<pgrid, pblock, 0, stream>>>(x0,   W1r, W2r, b1, b2, gt, yobs, mask, out_x, cpart + 0 * PROW, 1);
    phi_mfma<<<pgrid, pblock, 0, stream>>>(out_x,W1r, W2r, b1, b2, gt, yobs, mask, wsA,   cpart + 1 * PROW, 1);
    phi_mfma<<<pgrid, pblock, 0, stream>>>(wsA,  W1r, W2r, b1, b2, gt, yobs, mask, out_x, cpart + 2 * PROW, 1);
    phi_mfma<<<pgrid, pblock, 0, stream>>>(out_x,W1r, W2r, b1, b2, gt, yobs, mask, wsA,   cpart + 3 * PROW, 1);
    // x5 = phi(x4), no blend, no fused cost
    phi_mfma<<<pgrid, pblock, 0, stream>>>(wsA,  W1r, W2r, b1, b2, gt, yobs, mask, out_x, nullptr, 0);
    // cost(x5) -> row 4
    cost_kernel<<<cgrid, cblock, 0, stream>>>(out_x, gt, yobs, mask, cpart + 4 * PROW);

    finalize_kernel<<<dim3(5 * BD), dim3(256), 0, stream>>>(cpart, out_loss);
}